// Round 7
// baseline (753.531 us; speedup 1.0000x reference)
//
#include <hip/hip_runtime.h>
#include <cstdint>
#include <cstddef>

typedef __bf16 bf16_t;
typedef __bf16 bf16x4 __attribute__((ext_vector_type(4)));
typedef __bf16 bf16x8 __attribute__((ext_vector_type(8)));
typedef float f32x4 __attribute__((ext_vector_type(4)));

// ---------- transpose + f32->bf16: src f32 [R][C] -> dst bf16 [C][R] (R,C mult of 64) ----
__global__ __launch_bounds__(256) void transpose_cvt_k(const float* __restrict__ src,
                                                       bf16_t* __restrict__ dst, int R, int C) {
  __shared__ float t[64][65];
  const int tid = threadIdx.x;
  const int tr = blockIdx.y * 64, tc = blockIdx.x * 64;
  const int r0 = tid >> 2, c0 = (tid & 3) * 16;
#pragma unroll
  for (int i = 0; i < 16; i += 4) {
    float4 v = *(const float4*)(src + (size_t)(tr + r0) * C + tc + c0 + i);
    t[r0][c0 + i] = v.x; t[r0][c0 + i + 1] = v.y;
    t[r0][c0 + i + 2] = v.z; t[r0][c0 + i + 3] = v.w;
  }
  __syncthreads();
  bf16x8 w0, w1;
#pragma unroll
  for (int i = 0; i < 8; ++i) {
    w0[i] = (bf16_t)t[c0 + i][r0];
    w1[i] = (bf16_t)t[c0 + 8 + i][r0];
  }
  *(bf16x8*)(dst + (size_t)(tc + r0) * R + tr + c0) = w0;
  *(bf16x8*)(dst + (size_t)(tc + r0) * R + tr + c0 + 8) = w1;
}

// ---------- elementwise f32 -> bf16 ------------------------------------------------------
__global__ __launch_bounds__(256) void cvt_k(const float* __restrict__ in,
                                             bf16_t* __restrict__ out) {
  const size_t i = ((size_t)blockIdx.x * 256 + threadIdx.x) * 8;
  float4 a = *(const float4*)(in + i);
  float4 b = *(const float4*)(in + i + 4);
  bf16x8 o;
  o[0] = (bf16_t)a.x; o[1] = (bf16_t)a.y; o[2] = (bf16_t)a.z; o[3] = (bf16_t)a.w;
  o[4] = (bf16_t)b.x; o[5] = (bf16_t)b.y; o[6] = (bf16_t)b.z; o[7] = (bf16_t)b.w;
  *(bf16x8*)(out + i) = o;
}

// ---------------- GEMM: C[M x N] = A[M x K] @ Bt[N x K]^T + bias, fused epilogues -------
// EPI 0: QKV split-write to out0/1/2 (bf16) in [B][H][S][DK] layout, f32 bias per chunk
// EPI 1: out0[row,col] = bf16(acc + bias0[col] + (float)res[row,col])
// EPI 2: out0[row,col] = bf16(relu(acc + bias0[col]))
template <int EPI>
__global__ __launch_bounds__(256) void gemm_bt(
    const bf16_t* __restrict__ A, const bf16_t* __restrict__ Bt,
    const float* __restrict__ bias0, const float* __restrict__ bias1,
    const float* __restrict__ bias2, const bf16_t* __restrict__ res,
    bf16_t* __restrict__ out0, bf16_t* __restrict__ out1, bf16_t* __restrict__ out2,
    int N, int K) {
  __shared__ __align__(16) bf16_t As[128][64];
  __shared__ __align__(16) bf16_t Bs[128][64];
  const int tid = threadIdx.x, lane = tid & 63, wave = tid >> 6;
  const int wm = wave >> 1, wn = wave & 1;
  const int tile_m = blockIdx.y * 128, tile_n = blockIdx.x * 128;

  f32x4 acc[4][4];
#pragma unroll
  for (int i = 0; i < 4; ++i)
#pragma unroll
    for (int j = 0; j < 4; ++j)
#pragma unroll
      for (int c = 0; c < 4; ++c) acc[i][j][c] = 0.f;

  for (int k0 = 0; k0 < K; k0 += 64) {
    __syncthreads();  // prior iteration's LDS reads complete before overwrite
#pragma unroll
    for (int j = 0; j < 4; ++j) {
      const int c = j * 256 + tid, rr = c >> 3, cc = (c & 7) * 8;
      const bf16x8 va = *(const bf16x8*)(A + (size_t)(tile_m + rr) * K + k0 + cc);
      const bf16x8 vb = *(const bf16x8*)(Bt + (size_t)(tile_n + rr) * K + k0 + cc);
      *(bf16x8*)&As[rr][cc] = va;
      *(bf16x8*)&Bs[rr][cc] = vb;
    }
    __syncthreads();
#pragma unroll
    for (int kk = 0; kk < 2; ++kk) {
      bf16x8 a[4], b[4];
#pragma unroll
      for (int i = 0; i < 4; ++i)
        a[i] = *(const bf16x8*)&As[wm * 64 + i * 16 + (lane & 15)][kk * 32 + (lane >> 4) * 8];
#pragma unroll
      for (int i = 0; i < 4; ++i)
        b[i] = *(const bf16x8*)&Bs[wn * 64 + i * 16 + (lane & 15)][kk * 32 + (lane >> 4) * 8];
#pragma unroll
      for (int mi = 0; mi < 4; ++mi)
#pragma unroll
        for (int ni = 0; ni < 4; ++ni)
          acc[mi][ni] = __builtin_amdgcn_mfma_f32_16x16x32_bf16(a[mi], b[ni], acc[mi][ni], 0, 0, 0);
    }
  }

#pragma unroll
  for (int mi = 0; mi < 4; ++mi) {
#pragma unroll
    for (int ni = 0; ni < 4; ++ni) {
      const int col = tile_n + wn * 64 + ni * 16 + (lane & 15);
      const int rbase = tile_m + wm * 64 + mi * 16 + (lane >> 4) * 4;
      if constexpr (EPI == 0) {
        const int which = col >> 10, cc = col & 1023;
        const float* bp = which == 0 ? bias0 : (which == 1 ? bias1 : bias2);
        bf16_t* op = which == 0 ? out0 : (which == 1 ? out1 : out2);
        const float bv = bp[cc];
        const int h = cc >> 6, dk = cc & 63;
#pragma unroll
        for (int r = 0; r < 4; ++r) {
          const int row = rbase + r, bb = row >> 11, ss = row & 2047;
          op[(((size_t)bb * 16 + h) * 2048 + ss) * 64 + dk] = (bf16_t)(acc[mi][ni][r] + bv);
        }
      } else {
        const float bv = bias0[col];
#pragma unroll
        for (int r = 0; r < 4; ++r) {
          const int row = rbase + r;
          float v = acc[mi][ni][r] + bv;
          if constexpr (EPI == 1) v += (float)res[(size_t)row * N + col];
          if constexpr (EPI == 2) v = v > 0.f ? v : 0.f;
          out0[(size_t)row * N + col] = (bf16_t)v;
        }
      }
    }
  }
}

// ---------------- flash attention: per-(b,h) per-128-q-tile block, 4 waves --------------
__global__ __launch_bounds__(256) void attn_k(
    const bf16_t* __restrict__ Q, const bf16_t* __restrict__ Kb, const bf16_t* __restrict__ Vb,
    const int* __restrict__ mask, bf16_t* __restrict__ ctxout) {
  __shared__ __align__(16) bf16_t Qs[128][64];
  __shared__ __align__(16) bf16_t Ks[64][64];
  __shared__ __align__(16) bf16_t Vt[64][64];  // transposed V tile: Vt[d][kpos]
  __shared__ __align__(16) bf16_t Ps[128][64];
  const int tid = threadIdx.x, lane = tid & 63, wave = tid >> 6;
  const int qt = blockIdx.x, bh = blockIdx.y, b = bh >> 4, h = bh & 15;
  const bf16_t* qbase = Q + ((size_t)bh * 2048 + qt * 128) * 64;
  const bf16_t* kbase = Kb + (size_t)bh * 2048 * 64;
  const bf16_t* vbase = Vb + (size_t)bh * 2048 * 64;
  const int* mbase = mask + b * 2048;

#pragma unroll
  for (int j = 0; j < 4; ++j) {
    const int c = j * 256 + tid;
    *(bf16x8*)&Qs[c >> 3][(c & 7) * 8] = *(const bf16x8*)(qbase + c * 8);
  }

  f32x4 ctx[2][4];
  float m_run[2][4], l_run[2][4];
#pragma unroll
  for (int mi = 0; mi < 2; ++mi)
#pragma unroll
    for (int r = 0; r < 4; ++r) {
      m_run[mi][r] = -1e30f;
      l_run[mi][r] = 0.f;
#pragma unroll
      for (int di = 0; di < 4; ++di) ctx[mi][di][r] = 0.f;
    }

  for (int kt = 0; kt < 32; ++kt) {
    __syncthreads();  // prior iteration's Ks/Vt/Ps reads complete before overwrite
#pragma unroll
    for (int j = 0; j < 2; ++j) {
      const int c = j * 256 + tid;
      *(bf16x8*)&Ks[c >> 3][(c & 7) * 8] =
          *(const bf16x8*)(kbase + (size_t)kt * 4096 + c * 8);
    }
#pragma unroll
    for (int j = 0; j < 2; ++j) {
      const int c = j * 256 + tid, kp = c >> 3, d0 = (c & 7) * 8;
      bf16x8 v = *(const bf16x8*)(vbase + (size_t)kt * 4096 + kp * 64 + d0);
#pragma unroll
      for (int i = 0; i < 8; ++i) Vt[d0 + i][kp] = v[i];
    }
    __syncthreads();

    // scores: S[q][k] for this wave's 32 q-rows x 64 k-cols
    f32x4 sc[2][4];
#pragma unroll
    for (int mi = 0; mi < 2; ++mi)
#pragma unroll
      for (int ni = 0; ni < 4; ++ni)
#pragma unroll
        for (int c = 0; c < 4; ++c) sc[mi][ni][c] = 0.f;
#pragma unroll
    for (int kk = 0; kk < 2; ++kk) {
      bf16x8 aq[2], kb_[4];
#pragma unroll
      for (int mi = 0; mi < 2; ++mi)
        aq[mi] = *(const bf16x8*)&Qs[wave * 32 + mi * 16 + (lane & 15)][kk * 32 + (lane >> 4) * 8];
#pragma unroll
      for (int ni = 0; ni < 4; ++ni)
        kb_[ni] = *(const bf16x8*)&Ks[ni * 16 + (lane & 15)][kk * 32 + (lane >> 4) * 8];
#pragma unroll
      for (int mi = 0; mi < 2; ++mi)
#pragma unroll
        for (int ni = 0; ni < 4; ++ni)
          sc[mi][ni] = __builtin_amdgcn_mfma_f32_16x16x32_bf16(aq[mi], kb_[ni], sc[mi][ni], 0, 0, 0);
    }

    int mv[4];
#pragma unroll
    for (int ni = 0; ni < 4; ++ni) mv[ni] = mbase[kt * 64 + ni * 16 + (lane & 15)];

#pragma unroll
    for (int mi = 0; mi < 2; ++mi) {
#pragma unroll
      for (int ni = 0; ni < 4; ++ni)
#pragma unroll
        for (int r = 0; r < 4; ++r) {
          const float s = sc[mi][ni][r] * 0.125f;
          sc[mi][ni][r] = mv[ni] ? s : -1e9f;
        }
#pragma unroll
      for (int r = 0; r < 4; ++r) {
        float tmax = fmaxf(fmaxf(sc[mi][0][r], sc[mi][1][r]), fmaxf(sc[mi][2][r], sc[mi][3][r]));
#pragma unroll
        for (int d = 1; d < 16; d <<= 1) tmax = fmaxf(tmax, __shfl_xor(tmax, d));
        const float mnew = fmaxf(m_run[mi][r], tmax);
        const float scal = __expf(m_run[mi][r] - mnew);
        m_run[mi][r] = mnew;
        float rsum = 0.f;
#pragma unroll
        for (int ni = 0; ni < 4; ++ni) {
          const float p = __expf(sc[mi][ni][r] - mnew);
          sc[mi][ni][r] = p;
          rsum += p;
        }
#pragma unroll
        for (int d = 1; d < 16; d <<= 1) rsum += __shfl_xor(rsum, d);
        l_run[mi][r] = l_run[mi][r] * scal + rsum;
#pragma unroll
        for (int di = 0; di < 4; ++di) ctx[mi][di][r] *= scal;
      }
      const int qrow = wave * 32 + mi * 16 + (lane >> 4) * 4;
#pragma unroll
      for (int ni = 0; ni < 4; ++ni)
#pragma unroll
        for (int r = 0; r < 4; ++r)
          Ps[qrow + r][ni * 16 + (lane & 15)] = (bf16_t)sc[mi][ni][r];
    }
    __syncthreads();  // P writes visible before PV reads

    // PV: ctx += P @ V  (V from transposed LDS tile)
#pragma unroll
    for (int kk = 0; kk < 2; ++kk) {
      bf16x8 pa[2], vv[4];
#pragma unroll
      for (int mi = 0; mi < 2; ++mi)
        pa[mi] = *(const bf16x8*)&Ps[wave * 32 + mi * 16 + (lane & 15)][kk * 32 + (lane >> 4) * 8];
#pragma unroll
      for (int di = 0; di < 4; ++di)
        vv[di] = *(const bf16x8*)&Vt[di * 16 + (lane & 15)][kk * 32 + (lane >> 4) * 8];
#pragma unroll
      for (int mi = 0; mi < 2; ++mi)
#pragma unroll
        for (int di = 0; di < 4; ++di)
          ctx[mi][di] = __builtin_amdgcn_mfma_f32_16x16x32_bf16(pa[mi], vv[di], ctx[mi][di], 0, 0, 0);
    }
  }

#pragma unroll
  for (int mi = 0; mi < 2; ++mi)
#pragma unroll
    for (int r = 0; r < 4; ++r) {
      const float inv = 1.f / l_run[mi][r];
      const int srow = qt * 128 + wave * 32 + mi * 16 + (lane >> 4) * 4 + r;
#pragma unroll
      for (int di = 0; di < 4; ++di) {
        const int col = h * 64 + di * 16 + (lane & 15);
        ctxout[((size_t)b * 2048 + srow) * 1024 + col] = (bf16_t)(ctx[mi][di][r] * inv);
      }
    }
}

// ---------------- LayerNorm over D=1024 (bf16 in; bf16 or f32 out), one block per row ---
template <int F32OUT>
__global__ __launch_bounds__(256) void ln_k(const bf16_t* __restrict__ in,
                                            const float* __restrict__ g,
                                            const float* __restrict__ be,
                                            void* __restrict__ out) {
  __shared__ float red[8];
  const int tid = threadIdx.x;
  const size_t row = blockIdx.x;
  bf16x4 v4 = *(const bf16x4*)(in + row * 1024 + tid * 4);
  const float f0 = (float)v4[0], f1 = (float)v4[1], f2 = (float)v4[2], f3 = (float)v4[3];
  float s = f0 + f1 + f2 + f3;
  float s2 = f0 * f0 + f1 * f1 + f2 * f2 + f3 * f3;
#pragma unroll
  for (int d = 1; d < 64; d <<= 1) { s += __shfl_xor(s, d); s2 += __shfl_xor(s2, d); }
  if ((tid & 63) == 0) { red[tid >> 6] = s; red[4 + (tid >> 6)] = s2; }
  __syncthreads();
  s = red[0] + red[1] + red[2] + red[3];
  s2 = red[4] + red[5] + red[6] + red[7];
  const float mu = s * (1.f / 1024.f);
  const float var = s2 * (1.f / 1024.f) - mu * mu;
  const float rs = rsqrtf(var + 1e-5f);
  float4 gv = *(const float4*)(g + tid * 4);
  float4 bv = *(const float4*)(be + tid * 4);
  const float r0 = (f0 - mu) * rs * gv.x + bv.x;
  const float r1 = (f1 - mu) * rs * gv.y + bv.y;
  const float r2 = (f2 - mu) * rs * gv.z + bv.z;
  const float r3 = (f3 - mu) * rs * gv.w + bv.w;
  if constexpr (F32OUT) {
    float4 o = {r0, r1, r2, r3};
    *(float4*)((float*)out + row * 1024 + tid * 4) = o;
  } else {
    bf16x4 o;
    o[0] = (bf16_t)r0; o[1] = (bf16_t)r1; o[2] = (bf16_t)r2; o[3] = (bf16_t)r3;
    *(bf16x4*)((bf16_t*)out + row * 1024 + tid * 4) = o;
  }
}

extern "C" void kernel_launch(void* const* d_in, const int* in_sizes, int n_in,
                              void* d_out, int out_size, void* d_ws, size_t ws_size,
                              hipStream_t stream) {
  const float* x    = (const float*)d_in[0];
  const int*   mask = (const int*)d_in[1];
  const float* wq = (const float*)d_in[2];
  const float* bq = (const float*)d_in[3];
  const float* wk = (const float*)d_in[4];
  const float* bk = (const float*)d_in[5];
  const float* wv = (const float*)d_in[6];
  const float* bv = (const float*)d_in[7];
  const float* wo = (const float*)d_in[8];
  const float* bo = (const float*)d_in[9];
  const float* w1 = (const float*)d_in[10];
  const float* b1 = (const float*)d_in[11];
  const float* w2 = (const float*)d_in[12];
  const float* b2 = (const float*)d_in[13];
  const float* g1  = (const float*)d_in[14];
  const float* be1 = (const float*)d_in[15];
  const float* g2  = (const float*)d_in[16];
  const float* be2 = (const float*)d_in[17];

  char* wsb = (char*)d_ws;
  // ws layout (bytes), peak = 125,829,120 (within previously verified ws_size):
  //   S0  [0, 8388608)            weight-transpose scratch, serially reused
  //   XB  [8388608, 25165824)     bf16(x)
  //   QB/KB/VB/CTX 16.7MB each    [25165824, 92274688); FFN (67.1MB) overlays all four
  //   Y   [92274688, 109051904)   bf16 residual sums
  //   O1  [109051904, 125829120)  bf16 LN1 out
  bf16_t* S0  = (bf16_t*)wsb;
  bf16_t* XB  = (bf16_t*)(wsb + 8388608);
  bf16_t* QB  = (bf16_t*)(wsb + 25165824);
  bf16_t* KB  = (bf16_t*)(wsb + 41943040);
  bf16_t* VB  = (bf16_t*)(wsb + 58720256);
  bf16_t* CTX = (bf16_t*)(wsb + 75497472);
  bf16_t* FFN = QB;
  bf16_t* Y   = (bf16_t*)(wsb + 92274688);
  bf16_t* O1  = (bf16_t*)(wsb + 109051904);

  dim3 blk(256);
  cvt_k<<<4096, blk, 0, stream>>>(x, XB);
  // wq^T | wk^T | wv^T stacked into S0 ([3072][1024])
  transpose_cvt_k<<<dim3(16, 16), blk, 0, stream>>>(wq, S0, 1024, 1024);
  transpose_cvt_k<<<dim3(16, 16), blk, 0, stream>>>(wk, S0 + 1048576, 1024, 1024);
  transpose_cvt_k<<<dim3(16, 16), blk, 0, stream>>>(wv, S0 + 2097152, 1024, 1024);
  // QKV projection: XB @ [wq|wk|wv] + bias -> Q/K/V (bf16, [B][H][S][DK])
  gemm_bt<0><<<dim3(24, 64), blk, 0, stream>>>(XB, S0, bq, bk, bv, nullptr,
                                               QB, KB, VB, 3072, 1024);
  transpose_cvt_k<<<dim3(16, 16), blk, 0, stream>>>(wo, S0, 1024, 1024);  // WOT
  attn_k<<<dim3(16, 64), blk, 0, stream>>>(QB, KB, VB, mask, CTX);
  // out-proj + residual(XB) -> Y (bf16)
  gemm_bt<1><<<dim3(8, 64), blk, 0, stream>>>(CTX, S0, bo, nullptr, nullptr, XB,
                                              Y, nullptr, nullptr, 1024, 1024);
  transpose_cvt_k<<<dim3(64, 16), blk, 0, stream>>>(w1, S0, 1024, 4096);  // W1T
  ln_k<0><<<8192, blk, 0, stream>>>(Y, g1, be1, O1);
  // FFN1 + ReLU -> FFN (bf16, overlays QB..CTX)
  gemm_bt<2><<<dim3(32, 64), blk, 0, stream>>>(O1, S0, b1, nullptr, nullptr, nullptr,
                                               FFN, nullptr, nullptr, 4096, 1024);
  transpose_cvt_k<<<dim3(16, 64), blk, 0, stream>>>(w2, S0, 4096, 1024);  // W2T
  // FFN2 + residual(O1) -> Y (bf16)
  gemm_bt<1><<<dim3(8, 64), blk, 0, stream>>>(FFN, S0, b2, nullptr, nullptr, O1,
                                              Y, nullptr, nullptr, 1024, 4096);
  // final LN -> d_out as FLOAT32 (the reference's output dtype)
  ln_k<1><<<8192, blk, 0, stream>>>(Y, g2, be2, d_out);
}

// Round 8
// 590.175 us; speedup vs baseline: 1.2768x; 1.2768x over previous
//
#include <hip/hip_runtime.h>
#include <cstdint>
#include <cstddef>

typedef __bf16 bf16_t;
typedef __bf16 bf16x4 __attribute__((ext_vector_type(4)));
typedef __bf16 bf16x8 __attribute__((ext_vector_type(8)));
typedef float f32x4 __attribute__((ext_vector_type(4)));

// async global->LDS, 16B/lane; LDS dest = wave-uniform base, HW adds lane*16
#define GLD_LDS16(g, l)                                                                   \
  __builtin_amdgcn_global_load_lds((const __attribute__((address_space(1))) void*)(g),   \
                                   (__attribute__((address_space(3))) void*)(l), 16, 0, 0)

// LDS XOR swizzle for [R][64]bf16 (128B rows): spreads both 16-row fragment reads
// and 8-row-stride transpose writes across 8 16B slots.
__device__ __forceinline__ int swz(int row, int colbyte) {
  return row * 128 + (colbyte ^ (((row ^ (row >> 3)) & 7) << 4));
}
__device__ __forceinline__ int swbits(int row) {
  return ((row ^ (row >> 3)) & 7) << 4;
}

// ---------- transpose + f32->bf16: src f32 [R][C] -> dst bf16 [C][R] --------------------
__global__ __launch_bounds__(256) void transpose_cvt_k(const float* __restrict__ src,
                                                       bf16_t* __restrict__ dst, int R, int C) {
  __shared__ float t[64][65];
  const int tid = threadIdx.x;
  const int tr = blockIdx.y * 64, tc = blockIdx.x * 64;
  const int r0 = tid >> 2, c0 = (tid & 3) * 16;
#pragma unroll
  for (int i = 0; i < 16; i += 4) {
    float4 v = *(const float4*)(src + (size_t)(tr + r0) * C + tc + c0 + i);
    t[r0][c0 + i] = v.x; t[r0][c0 + i + 1] = v.y;
    t[r0][c0 + i + 2] = v.z; t[r0][c0 + i + 3] = v.w;
  }
  __syncthreads();
  bf16x8 w0, w1;
#pragma unroll
  for (int i = 0; i < 8; ++i) {
    w0[i] = (bf16_t)t[c0 + i][r0];
    w1[i] = (bf16_t)t[c0 + 8 + i][r0];
  }
  *(bf16x8*)(dst + (size_t)(tc + r0) * R + tr + c0) = w0;
  *(bf16x8*)(dst + (size_t)(tc + r0) * R + tr + c0 + 8) = w1;
}

// ---------- elementwise f32 -> bf16 ------------------------------------------------------
__global__ __launch_bounds__(256) void cvt_k(const float* __restrict__ in,
                                             bf16_t* __restrict__ out) {
  const size_t i = ((size_t)blockIdx.x * 256 + threadIdx.x) * 8;
  float4 a = *(const float4*)(in + i);
  float4 b = *(const float4*)(in + i + 4);
  bf16x8 o;
  o[0] = (bf16_t)a.x; o[1] = (bf16_t)a.y; o[2] = (bf16_t)a.z; o[3] = (bf16_t)a.w;
  o[4] = (bf16_t)b.x; o[5] = (bf16_t)b.y; o[6] = (bf16_t)b.z; o[7] = (bf16_t)b.w;
  *(bf16x8*)(out + i) = o;
}

// ---------------- GEMM: C[M x N] = A[M x K] @ Bt[N x K]^T + bias, fused epilogues -------
template <int EPI>
__global__ __launch_bounds__(256) void gemm_bt(
    const bf16_t* __restrict__ A, const bf16_t* __restrict__ Bt,
    const float* __restrict__ bias0, const float* __restrict__ bias1,
    const float* __restrict__ bias2, const bf16_t* __restrict__ res,
    bf16_t* __restrict__ out0, bf16_t* __restrict__ out1, bf16_t* __restrict__ out2,
    int N, int K) {
  __shared__ __align__(16) bf16_t As[128][64];
  __shared__ __align__(16) bf16_t Bs[128][64];
  const int tid = threadIdx.x, lane = tid & 63, wave = tid >> 6;
  const int wm = wave >> 1, wn = wave & 1;
  const int tile_m = blockIdx.y * 128, tile_n = blockIdx.x * 128;

  f32x4 acc[4][4];
#pragma unroll
  for (int i = 0; i < 4; ++i)
#pragma unroll
    for (int j = 0; j < 4; ++j)
#pragma unroll
      for (int c = 0; c < 4; ++c) acc[i][j][c] = 0.f;

  for (int k0 = 0; k0 < K; k0 += 64) {
    __syncthreads();  // prior iteration's LDS reads complete before overwrite
#pragma unroll
    for (int j = 0; j < 4; ++j) {
      const int c = j * 256 + tid;
      GLD_LDS16(A + (size_t)(tile_m + (c >> 3)) * K + k0 + (c & 7) * 8,
                (char*)As + j * 4096 + wave * 1024);
      GLD_LDS16(Bt + (size_t)(tile_n + (c >> 3)) * K + k0 + (c & 7) * 8,
                (char*)Bs + j * 4096 + wave * 1024);
    }
    __syncthreads();  // drains vmcnt -> staged data visible
#pragma unroll
    for (int kk = 0; kk < 2; ++kk) {
      bf16x8 a[4], b[4];
#pragma unroll
      for (int i = 0; i < 4; ++i)
        a[i] = *(const bf16x8*)&As[wm * 64 + i * 16 + (lane & 15)][kk * 32 + (lane >> 4) * 8];
#pragma unroll
      for (int i = 0; i < 4; ++i)
        b[i] = *(const bf16x8*)&Bs[wn * 64 + i * 16 + (lane & 15)][kk * 32 + (lane >> 4) * 8];
#pragma unroll
      for (int mi = 0; mi < 4; ++mi)
#pragma unroll
        for (int ni = 0; ni < 4; ++ni)
          acc[mi][ni] = __builtin_amdgcn_mfma_f32_16x16x32_bf16(a[mi], b[ni], acc[mi][ni], 0, 0, 0);
    }
  }

#pragma unroll
  for (int mi = 0; mi < 4; ++mi) {
#pragma unroll
    for (int ni = 0; ni < 4; ++ni) {
      const int col = tile_n + wn * 64 + ni * 16 + (lane & 15);
      const int rbase = tile_m + wm * 64 + mi * 16 + (lane >> 4) * 4;
      if constexpr (EPI == 0) {
        const int which = col >> 10, cc = col & 1023;
        const float* bp = which == 0 ? bias0 : (which == 1 ? bias1 : bias2);
        bf16_t* op = which == 0 ? out0 : (which == 1 ? out1 : out2);
        const float bv = bp[cc];
        const int h = cc >> 6, dk = cc & 63;
#pragma unroll
        for (int r = 0; r < 4; ++r) {
          const int row = rbase + r, bb = row >> 11, ss = row & 2047;
          op[(((size_t)bb * 16 + h) * 2048 + ss) * 64 + dk] = (bf16_t)(acc[mi][ni][r] + bv);
        }
      } else {
        const float bv = bias0[col];
#pragma unroll
        for (int r = 0; r < 4; ++r) {
          const int row = rbase + r;
          float v = acc[mi][ni][r] + bv;
          if constexpr (EPI == 1) v += (float)res[(size_t)row * N + col];
          if constexpr (EPI == 2) v = v > 0.f ? v : 0.f;
          out0[(size_t)row * N + col] = (bf16_t)v;
        }
      }
    }
  }
}

// ---------------- flash attention: per-(b,h) per-128-q-tile block, 4 waves --------------
// All LDS tiles XOR-swizzled (128B rows were a 16-way read conflict).
// Q/K staged by global_load_lds with PRE-SWIZZLED global source (LDS dest stays linear);
// Vt/Ps written by lanes with the same swizzle.
__global__ __launch_bounds__(256) void attn_k(
    const bf16_t* __restrict__ Q, const bf16_t* __restrict__ Kb, const bf16_t* __restrict__ Vb,
    const int* __restrict__ mask, bf16_t* __restrict__ ctxout) {
  __shared__ __align__(16) char Qs[16384];  // [128][64] bf16, swizzled
  __shared__ __align__(16) char Ks[8192];   // [64][64]
  __shared__ __align__(16) char Vt[8192];   // [64(d)][64(k)] transposed V, swizzled
  __shared__ __align__(16) char Ps[16384];  // [128][64]
  const int tid = threadIdx.x, lane = tid & 63, wave = tid >> 6;
  const int fr = lane & 15, hi = lane >> 4;
  const int qt = blockIdx.x, bh = blockIdx.y, b = bh >> 4, h = bh & 15;
  const bf16_t* qbase = Q + ((size_t)bh * 2048 + qt * 128) * 64;
  const bf16_t* kbase = Kb + (size_t)bh * 2048 * 64;
  const bf16_t* vbase = Vb + (size_t)bh * 2048 * 64;
  const int* mbase = mask + b * 2048;

  // Q stage: LDS linear byte c*16 must hold Q[rr][ (cb ^ S(rr)) ] -> pre-swizzle source
#pragma unroll
  for (int j = 0; j < 4; ++j) {
    const int c = j * 256 + tid, rr = c >> 3, cb = (c & 7) * 16;
    const int scb = cb ^ swbits(rr);
    GLD_LDS16(qbase + rr * 64 + (scb >> 1), Qs + j * 4096 + wave * 1024);
  }

  f32x4 ctx[2][4];
  float m_run[2][4], l_run[2][4];
#pragma unroll
  for (int mi = 0; mi < 2; ++mi)
#pragma unroll
    for (int r = 0; r < 4; ++r) {
      m_run[mi][r] = -1e30f;
      l_run[mi][r] = 0.f;
#pragma unroll
      for (int di = 0; di < 4; ++di) ctx[mi][di][r] = 0.f;
    }

  for (int kt = 0; kt < 32; ++kt) {
    __syncthreads();  // prior iter's reads done; also drains Q/K gload_lds (vmcnt0 at barrier)
#pragma unroll
    for (int j = 0; j < 2; ++j) {
      const int c = j * 256 + tid, rr = c >> 3, cb = (c & 7) * 16;
      const int scb = cb ^ swbits(rr);
      GLD_LDS16(kbase + (size_t)kt * 4096 + rr * 64 + (scb >> 1),
                Ks + j * 4096 + wave * 1024);
    }
#pragma unroll
    for (int j = 0; j < 2; ++j) {
      const int c = j * 256 + tid, kp = c >> 3, d0 = (c & 7) * 8;
      bf16x8 v = *(const bf16x8*)(vbase + (size_t)kt * 4096 + kp * 64 + d0);
#pragma unroll
      for (int i = 0; i < 8; ++i)
        *(bf16_t*)(Vt + swz(d0 + i, kp * 2)) = v[i];
    }
    __syncthreads();

    // scores: S[q][k] for this wave's 32 q-rows x 64 k-cols
    f32x4 sc[2][4];
#pragma unroll
    for (int mi = 0; mi < 2; ++mi)
#pragma unroll
      for (int ni = 0; ni < 4; ++ni)
#pragma unroll
        for (int c = 0; c < 4; ++c) sc[mi][ni][c] = 0.f;
#pragma unroll
    for (int kk = 0; kk < 2; ++kk) {
      bf16x8 aq[2], kb_[4];
#pragma unroll
      for (int mi = 0; mi < 2; ++mi)
        aq[mi] = *(const bf16x8*)(Qs + swz(wave * 32 + mi * 16 + fr, kk * 64 + hi * 16));
#pragma unroll
      for (int ni = 0; ni < 4; ++ni)
        kb_[ni] = *(const bf16x8*)(Ks + swz(ni * 16 + fr, kk * 64 + hi * 16));
#pragma unroll
      for (int mi = 0; mi < 2; ++mi)
#pragma unroll
        for (int ni = 0; ni < 4; ++ni)
          sc[mi][ni] = __builtin_amdgcn_mfma_f32_16x16x32_bf16(aq[mi], kb_[ni], sc[mi][ni], 0, 0, 0);
    }

    int mv[4];
#pragma unroll
    for (int ni = 0; ni < 4; ++ni) mv[ni] = mbase[kt * 64 + ni * 16 + fr];

#pragma unroll
    for (int mi = 0; mi < 2; ++mi) {
#pragma unroll
      for (int ni = 0; ni < 4; ++ni)
#pragma unroll
        for (int r = 0; r < 4; ++r) {
          const float s = sc[mi][ni][r] * 0.125f;
          sc[mi][ni][r] = mv[ni] ? s : -1e9f;
        }
#pragma unroll
      for (int r = 0; r < 4; ++r) {
        float tmax = fmaxf(fmaxf(sc[mi][0][r], sc[mi][1][r]), fmaxf(sc[mi][2][r], sc[mi][3][r]));
#pragma unroll
        for (int d = 1; d < 16; d <<= 1) tmax = fmaxf(tmax, __shfl_xor(tmax, d));
        const float mnew = fmaxf(m_run[mi][r], tmax);
        const float scal = __expf(m_run[mi][r] - mnew);
        m_run[mi][r] = mnew;
        float rsum = 0.f;
#pragma unroll
        for (int ni = 0; ni < 4; ++ni) {
          const float p = __expf(sc[mi][ni][r] - mnew);
          sc[mi][ni][r] = p;
          rsum += p;
        }
#pragma unroll
        for (int d = 1; d < 16; d <<= 1) rsum += __shfl_xor(rsum, d);
        l_run[mi][r] = l_run[mi][r] * scal + rsum;
#pragma unroll
        for (int di = 0; di < 4; ++di) ctx[mi][di][r] *= scal;
      }
      const int qrow = wave * 32 + mi * 16 + hi * 4;
#pragma unroll
      for (int ni = 0; ni < 4; ++ni)
#pragma unroll
        for (int r = 0; r < 4; ++r)
          *(bf16_t*)(Ps + swz(qrow + r, (ni * 16 + fr) * 2)) = (bf16_t)sc[mi][ni][r];
    }
    __syncthreads();  // P writes visible before PV reads

    // PV: ctx += P @ V
#pragma unroll
    for (int kk = 0; kk < 2; ++kk) {
      bf16x8 pa[2], vv[4];
#pragma unroll
      for (int mi = 0; mi < 2; ++mi)
        pa[mi] = *(const bf16x8*)(Ps + swz(wave * 32 + mi * 16 + fr, kk * 64 + hi * 16));
#pragma unroll
      for (int di = 0; di < 4; ++di)
        vv[di] = *(const bf16x8*)(Vt + swz(di * 16 + fr, kk * 64 + hi * 16));
#pragma unroll
      for (int mi = 0; mi < 2; ++mi)
#pragma unroll
        for (int di = 0; di < 4; ++di)
          ctx[mi][di] = __builtin_amdgcn_mfma_f32_16x16x32_bf16(pa[mi], vv[di], ctx[mi][di], 0, 0, 0);
    }
  }

#pragma unroll
  for (int mi = 0; mi < 2; ++mi)
#pragma unroll
    for (int r = 0; r < 4; ++r) {
      const float inv = 1.f / l_run[mi][r];
      const int srow = qt * 128 + wave * 32 + mi * 16 + hi * 4 + r;
#pragma unroll
      for (int di = 0; di < 4; ++di) {
        const int col = h * 64 + di * 16 + fr;
        ctxout[((size_t)b * 2048 + srow) * 1024 + col] = (bf16_t)(ctx[mi][di][r] * inv);
      }
    }
}

// ---------------- LayerNorm over D=1024 (bf16 in; bf16 or f32 out), one block per row ---
template <int F32OUT>
__global__ __launch_bounds__(256) void ln_k(const bf16_t* __restrict__ in,
                                            const float* __restrict__ g,
                                            const float* __restrict__ be,
                                            void* __restrict__ out) {
  __shared__ float red[8];
  const int tid = threadIdx.x;
  const size_t row = blockIdx.x;
  bf16x4 v4 = *(const bf16x4*)(in + row * 1024 + tid * 4);
  const float f0 = (float)v4[0], f1 = (float)v4[1], f2 = (float)v4[2], f3 = (float)v4[3];
  float s = f0 + f1 + f2 + f3;
  float s2 = f0 * f0 + f1 * f1 + f2 * f2 + f3 * f3;
#pragma unroll
  for (int d = 1; d < 64; d <<= 1) { s += __shfl_xor(s, d); s2 += __shfl_xor(s2, d); }
  if ((tid & 63) == 0) { red[tid >> 6] = s; red[4 + (tid >> 6)] = s2; }
  __syncthreads();
  s = red[0] + red[1] + red[2] + red[3];
  s2 = red[4] + red[5] + red[6] + red[7];
  const float mu = s * (1.f / 1024.f);
  const float var = s2 * (1.f / 1024.f) - mu * mu;
  const float rs = rsqrtf(var + 1e-5f);
  float4 gv = *(const float4*)(g + tid * 4);
  float4 bv = *(const float4*)(be + tid * 4);
  const float r0 = (f0 - mu) * rs * gv.x + bv.x;
  const float r1 = (f1 - mu) * rs * gv.y + bv.y;
  const float r2 = (f2 - mu) * rs * gv.z + bv.z;
  const float r3 = (f3 - mu) * rs * gv.w + bv.w;
  if constexpr (F32OUT) {
    float4 o = {r0, r1, r2, r3};
    *(float4*)((float*)out + row * 1024 + tid * 4) = o;
  } else {
    bf16x4 o;
    o[0] = (bf16_t)r0; o[1] = (bf16_t)r1; o[2] = (bf16_t)r2; o[3] = (bf16_t)r3;
    *(bf16x4*)((bf16_t*)out + row * 1024 + tid * 4) = o;
  }
}

extern "C" void kernel_launch(void* const* d_in, const int* in_sizes, int n_in,
                              void* d_out, int out_size, void* d_ws, size_t ws_size,
                              hipStream_t stream) {
  const float* x    = (const float*)d_in[0];
  const int*   mask = (const int*)d_in[1];
  const float* wq = (const float*)d_in[2];
  const float* bq = (const float*)d_in[3];
  const float* wk = (const float*)d_in[4];
  const float* bk = (const float*)d_in[5];
  const float* wv = (const float*)d_in[6];
  const float* bv = (const float*)d_in[7];
  const float* wo = (const float*)d_in[8];
  const float* bo = (const float*)d_in[9];
  const float* w1 = (const float*)d_in[10];
  const float* b1 = (const float*)d_in[11];
  const float* w2 = (const float*)d_in[12];
  const float* b2 = (const float*)d_in[13];
  const float* g1  = (const float*)d_in[14];
  const float* be1 = (const float*)d_in[15];
  const float* g2  = (const float*)d_in[16];
  const float* be2 = (const float*)d_in[17];

  char* wsb = (char*)d_ws;
  bf16_t* S0  = (bf16_t*)wsb;                 // weight-transpose scratch, serially reused
  bf16_t* XB  = (bf16_t*)(wsb + 8388608);     // bf16(x)
  bf16_t* QB  = (bf16_t*)(wsb + 25165824);
  bf16_t* KB  = (bf16_t*)(wsb + 41943040);
  bf16_t* VB  = (bf16_t*)(wsb + 58720256);
  bf16_t* CTX = (bf16_t*)(wsb + 75497472);
  bf16_t* FFN = QB;                           // overlays QB..CTX
  bf16_t* Y   = (bf16_t*)(wsb + 92274688);
  bf16_t* O1  = (bf16_t*)(wsb + 109051904);

  dim3 blk(256);
  cvt_k<<<4096, blk, 0, stream>>>(x, XB);
  transpose_cvt_k<<<dim3(16, 16), blk, 0, stream>>>(wq, S0, 1024, 1024);
  transpose_cvt_k<<<dim3(16, 16), blk, 0, stream>>>(wk, S0 + 1048576, 1024, 1024);
  transpose_cvt_k<<<dim3(16, 16), blk, 0, stream>>>(wv, S0 + 2097152, 1024, 1024);
  gemm_bt<0><<<dim3(24, 64), blk, 0, stream>>>(XB, S0, bq, bk, bv, nullptr,
                                               QB, KB, VB, 3072, 1024);
  transpose_cvt_k<<<dim3(16, 16), blk, 0, stream>>>(wo, S0, 1024, 1024);  // WOT
  attn_k<<<dim3(16, 64), blk, 0, stream>>>(QB, KB, VB, mask, CTX);
  gemm_bt<1><<<dim3(8, 64), blk, 0, stream>>>(CTX, S0, bo, nullptr, nullptr, XB,
                                              Y, nullptr, nullptr, 1024, 1024);
  transpose_cvt_k<<<dim3(64, 16), blk, 0, stream>>>(w1, S0, 1024, 4096);  // W1T
  ln_k<0><<<8192, blk, 0, stream>>>(Y, g1, be1, O1);
  gemm_bt<2><<<dim3(32, 64), blk, 0, stream>>>(O1, S0, b1, nullptr, nullptr, nullptr,
                                               FFN, nullptr, nullptr, 4096, 1024);
  transpose_cvt_k<<<dim3(16, 64), blk, 0, stream>>>(w2, S0, 4096, 1024);  // W2T
  gemm_bt<1><<<dim3(8, 64), blk, 0, stream>>>(FFN, S0, b2, nullptr, nullptr, O1,
                                              Y, nullptr, nullptr, 1024, 4096);
  ln_k<1><<<8192, blk, 0, stream>>>(Y, g2, be2, d_out);
}